// Round 1
// baseline (293.250 us; speedup 1.0000x reference)
//
#include <hip/hip_runtime.h>

// Problem constants (from reference): x (16,192,128) f32, W (2,1), b (2,), T=25
constexpr int Bn = 16;
constexpr int L  = 192;
constexpr int E  = 128;
constexpr int T  = 25;
constexpr int NI = L - T - 1;               // 166 shifted positions
constexpr int ROWS_OUT = (T + 1) + NI * L;  // 26 + 31872 = 31898
constexpr int E4 = E / 4;                   // 32 float4 per row

// Main kernel:
//   blocks 0 .. Bn*L-1      : one (b,l) pair each; 256 threads = 32 e4-slots x 8 i-slots.
//     Each thread computes s0 = sigmoid(x*(W1-W0)+(b1-b0)) ONCE for its 4 e-lanes,
//     then loops i += 8 writing out[b, 26 + i*L + l, e] = xp + (xi-xp)*s0.
//   blocks >= Bn*L          : prefix copy out[b, 0:26, :] = x[b, 0:26, :]  (13312 float4)
__global__ __launch_bounds__(256) void seasonality_kernel(
    const float* __restrict__ x,
    const float* __restrict__ W,
    const float* __restrict__ bv,
    float* __restrict__ out)
{
    const int blk = blockIdx.x;
    const int t = threadIdx.x;

    if (blk < Bn * L) {
        const int b = blk / L;
        const int l = blk % L;
        const int e4 = t & (E4 - 1);  // 0..31  (float4 column)
        const int i0 = t >> 5;        // 0..7   (i phase)

        const float4* __restrict__ xb = (const float4*)(x + (size_t)b * L * E);
        float4* __restrict__ ob = (float4*)(out + (size_t)b * ROWS_OUT * E);

        // softmax over 2 logits -> sigmoid of logit difference
        const float dw = W[1] - W[0];
        const float db = bv[1] - bv[0];
        const float4 xv = xb[(size_t)l * E4 + e4];
        float4 s0;
        s0.x = 1.0f / (1.0f + expf(xv.x * dw + db));
        s0.y = 1.0f / (1.0f + expf(xv.y * dw + db));
        s0.z = 1.0f / (1.0f + expf(xv.z * dw + db));
        s0.w = 1.0f / (1.0f + expf(xv.w * dw + db));

        // out row for (i, l): 26 + i*L + l
        for (int i = i0; i < NI; i += 8) {
            const float4 xi = xb[(size_t)(T + 1 + i) * E4 + e4];  // x[b, 26+i, :]
            const float4 xp = xb[(size_t)(1 + i) * E4 + e4];      // x[b, 1+i,  :]
            float4 o;
            o.x = xp.x + (xi.x - xp.x) * s0.x;
            o.y = xp.y + (xi.y - xp.y) * s0.y;
            o.z = xp.z + (xi.z - xp.z) * s0.z;
            o.w = xp.w + (xi.w - xp.w) * s0.w;
            ob[(size_t)(T + 1 + i * L + l) * E4 + e4] = o;
        }
    } else {
        // prefix copy: out[:, 0:T+1, :] = x[:, 0:T+1, :]
        const int gid = (blk - Bn * L) * 256 + t;       // float4 index
        constexpr int per_b = (T + 1) * E4;             // 832 float4 per batch
        constexpr int total = Bn * per_b;               // 13312
        if (gid < total) {
            const int b = gid / per_b;
            const int r = gid % per_b;
            const float4* __restrict__ xb = (const float4*)(x + (size_t)b * L * E);
            float4* __restrict__ ob = (float4*)(out + (size_t)b * ROWS_OUT * E);
            ob[r] = xb[r];
        }
    }
}

extern "C" void kernel_launch(void* const* d_in, const int* in_sizes, int n_in,
                              void* d_out, int out_size, void* d_ws, size_t ws_size,
                              hipStream_t stream) {
    const float* x  = (const float*)d_in[0];
    const float* W  = (const float*)d_in[1];
    const float* bv = (const float*)d_in[2];
    float* out = (float*)d_out;

    constexpr int prefix_f4 = Bn * (T + 1) * E4;               // 13312
    constexpr int prefix_blocks = (prefix_f4 + 255) / 256;     // 52
    const int grid = Bn * L + prefix_blocks;                   // 3072 + 52

    seasonality_kernel<<<grid, 256, 0, stream>>>(x, W, bv, out);
}

// Round 3
// 267.587 us; speedup vs baseline: 1.0959x; 1.0959x over previous
//
#include <hip/hip_runtime.h>

// Reference: x (16,192,128) f32, W (2,1), b (2,), T=25
constexpr int Bn = 16;
constexpr int L  = 192;
constexpr int E  = 128;
constexpr int T  = 25;
constexpr int NI = L - T - 1;               // 166 shifted positions
constexpr int ROWS_OUT = (T + 1) + NI * L;  // 31898
constexpr int E4 = E / 4;                   // 32 float4 per row
constexpr int S_ELEMS = Bn * L * E;         // 393216 floats = 1.57 MB
constexpr int PLANE_F4 = L * E4;            // 6144 float4 per (b,i) block

typedef float f4 __attribute__((ext_vector_type(4)));  // native vector: OK for nontemporal builtins

// k1: s[b,l,e] = 1 / (1 + exp(x[b,l,e]*(W1-W0) + (b1-b0)))
__global__ __launch_bounds__(256) void sigmoid_kernel(
    const float* __restrict__ x,
    const float* __restrict__ W,
    const float* __restrict__ bv,
    float* __restrict__ s)
{
    const int g = blockIdx.x * 256 + threadIdx.x;   // float4 index
    if (g >= S_ELEMS / 4) return;
    const float dw = W[1] - W[0];
    const float db = bv[1] - bv[0];
    const f4 xv = ((const f4*)x)[g];
    f4 o;
    o.x = __builtin_amdgcn_rcpf(1.0f + __expf(fmaf(xv.x, dw, db)));
    o.y = __builtin_amdgcn_rcpf(1.0f + __expf(fmaf(xv.y, dw, db)));
    o.z = __builtin_amdgcn_rcpf(1.0f + __expf(fmaf(xv.z, dw, db)));
    o.w = __builtin_amdgcn_rcpf(1.0f + __expf(fmaf(xv.w, dw, db)));
    ((f4*)s)[g] = o;
}

// k2: block = (b,i) for blk < Bn*NI  -> writes 192 contiguous rows (96 KB linear).
//     blocks >= Bn*NI               -> prefix copy out[:, 0:26, :] = x[:, 0:26, :].
// out[b, 26+i*L+l, e] = xp[e] + (xi[e]-xp[e]) * s[b,l,e]
//   xi = x[b, 26+i, :], xp = x[b, 1+i, :]   (two 512B rows, register-resident)
__global__ __launch_bounds__(256) void blocks_kernel(
    const float* __restrict__ x,
    const float* __restrict__ s,
    float* __restrict__ out)
{
    const int blk = blockIdx.x;
    const int t = threadIdx.x;

    if (blk < Bn * NI) {
        const int b = blk / NI;
        const int i = blk % NI;
        const int e4 = t & (E4 - 1);

        const f4* __restrict__ xrow_i = (const f4*)(x + ((size_t)(b * L + T + 1 + i)) * E);
        const f4* __restrict__ xrow_p = (const f4*)(x + ((size_t)(b * L + 1 + i)) * E);
        const f4 xp4 = xrow_p[e4];
        const f4 xi4 = xrow_i[e4];
        const f4 d4 = xi4 - xp4;

        const f4* __restrict__ sp = (const f4*)(s) + (size_t)b * PLANE_F4;
        f4* __restrict__ ob = (f4*)(out) + ((size_t)b * ROWS_OUT + (T + 1) + (size_t)i * L) * E4;

        #pragma unroll 4
        for (int k = 0; k < PLANE_F4 / 256; ++k) {   // 24 iterations
            const int j = k * 256 + t;               // l*32 + e4, e4 fixed per thread
            const f4 s4 = sp[j];
            f4 o;
            o.x = fmaf(d4.x, s4.x, xp4.x);
            o.y = fmaf(d4.y, s4.y, xp4.y);
            o.z = fmaf(d4.z, s4.z, xp4.z);
            o.w = fmaf(d4.w, s4.w, xp4.w);
            __builtin_nontemporal_store(o, &ob[j]);
        }
    } else {
        // prefix copy: 16 * 26 * 32 = 13312 float4
        const int gid = (blk - Bn * NI) * 256 + t;
        constexpr int per_b = (T + 1) * E4;          // 832
        constexpr int total = Bn * per_b;            // 13312
        if (gid < total) {
            const int b = gid / per_b;
            const int r = gid % per_b;
            const f4* __restrict__ xb = (const f4*)(x + (size_t)b * L * E);
            f4* __restrict__ ob = (f4*)(out + (size_t)b * ROWS_OUT * E);
            __builtin_nontemporal_store(xb[r], &ob[r]);
        }
    }
}

// Fallback (ws too small): same write structure, sigmoid inline.
__global__ __launch_bounds__(256) void blocks_kernel_inline(
    const float* __restrict__ x,
    const float* __restrict__ W,
    const float* __restrict__ bv,
    float* __restrict__ out)
{
    const int blk = blockIdx.x;
    const int t = threadIdx.x;
    const float dw = W[1] - W[0];
    const float db = bv[1] - bv[0];

    if (blk < Bn * NI) {
        const int b = blk / NI;
        const int i = blk % NI;
        const int e4 = t & (E4 - 1);

        const f4* __restrict__ xrow_i = (const f4*)(x + ((size_t)(b * L + T + 1 + i)) * E);
        const f4* __restrict__ xrow_p = (const f4*)(x + ((size_t)(b * L + 1 + i)) * E);
        const f4 xp4 = xrow_p[e4];
        const f4 xi4 = xrow_i[e4];
        const f4 d4 = xi4 - xp4;

        const f4* __restrict__ xp_plane = (const f4*)(x) + (size_t)b * PLANE_F4;
        f4* __restrict__ ob = (f4*)(out) + ((size_t)b * ROWS_OUT + (T + 1) + (size_t)i * L) * E4;

        for (int k = 0; k < PLANE_F4 / 256; ++k) {
            const int j = k * 256 + t;
            const f4 xv = xp_plane[j];
            f4 o;
            o.x = fmaf(d4.x, __builtin_amdgcn_rcpf(1.0f + __expf(fmaf(xv.x, dw, db))), xp4.x);
            o.y = fmaf(d4.y, __builtin_amdgcn_rcpf(1.0f + __expf(fmaf(xv.y, dw, db))), xp4.y);
            o.z = fmaf(d4.z, __builtin_amdgcn_rcpf(1.0f + __expf(fmaf(xv.z, dw, db))), xp4.z);
            o.w = fmaf(d4.w, __builtin_amdgcn_rcpf(1.0f + __expf(fmaf(xv.w, dw, db))), xp4.w);
            __builtin_nontemporal_store(o, &ob[j]);
        }
    } else {
        const int gid = (blk - Bn * NI) * 256 + t;
        constexpr int per_b = (T + 1) * E4;
        constexpr int total = Bn * per_b;
        if (gid < total) {
            const int b = gid / per_b;
            const int r = gid % per_b;
            const f4* __restrict__ xb = (const f4*)(x + (size_t)b * L * E);
            f4* __restrict__ ob = (f4*)(out + (size_t)b * ROWS_OUT * E);
            __builtin_nontemporal_store(xb[r], &ob[r]);
        }
    }
}

extern "C" void kernel_launch(void* const* d_in, const int* in_sizes, int n_in,
                              void* d_out, int out_size, void* d_ws, size_t ws_size,
                              hipStream_t stream) {
    const float* x  = (const float*)d_in[0];
    const float* W  = (const float*)d_in[1];
    const float* bv = (const float*)d_in[2];
    float* out = (float*)d_out;

    constexpr int prefix_f4 = Bn * (T + 1) * E4;            // 13312
    constexpr int prefix_blocks = (prefix_f4 + 255) / 256;  // 52
    const int grid2 = Bn * NI + prefix_blocks;              // 2656 + 52

    if (ws_size >= (size_t)S_ELEMS * sizeof(float)) {
        float* s = (float*)d_ws;
        sigmoid_kernel<<<(S_ELEMS / 4 + 255) / 256, 256, 0, stream>>>(x, W, bv, s);
        blocks_kernel<<<grid2, 256, 0, stream>>>(x, s, out);
    } else {
        blocks_kernel_inline<<<grid2, 256, 0, stream>>>(x, W, bv, out);
    }
}